// Round 4
// baseline (474.011 us; speedup 1.0000x reference)
//
#include <hip/hip_runtime.h>
#include <hip/hip_bf16.h>

// Gram matrix: G = X @ X^T, X = [512, 65536] fp32, out = [512, 512] fp32.
// Round 4: fix the burst-drain memory pattern diagnosed in r1-r3 (LLC-warm
// replays were just as slow; per-iter time ~12k cyc vs ~1.5k compute model).
//  - double-buffered LDS, ONE barrier per iteration
//  - depth-2 register prefetch: loads for iter i+2 issue before the vmcnt
//    wait on iter i+1's regs -> memory queue never drains to zero
//  - symmetric tiling, 256 balanced blocks (1/CU): (0,0),(1,1) @ KC=1024;
//    (0,1) @ KC=512 x 2 chunks, mirrored into (1,0) by the epilogue.
//    Every block loads exactly 1 MB. Logical reads 384->256 MB.
//  - blocks 4g..4g+3 share columns [1024g,1024(g+1)) -> LLC absorbs overlap.
// Note: SQ_LDS_BANK_CONFLICT ~= 8/ds_read_b128 is inherent (256dw/32banks),
// identical across strides -- not actionable.

typedef short bf16x8 __attribute__((ext_vector_type(8)));   // 8 bf16 = 4 VGPRs
typedef float f32x4  __attribute__((ext_vector_type(4)));   // MFMA acc

#define HW      65536
#define CDIM    512
#define BM      256
#define BK      32
#define LDSS    34               // LDS row stride in bf16 = 17 dwords (odd)
#define PANEL   (BM * LDSS)      // shorts per panel buffer

__device__ __forceinline__ short f2bf(float f) {
    __hip_bfloat16 h = __float2bfloat16(f);   // RNE
    short s;
    __builtin_memcpy(&s, &h, sizeof(short));
    return s;
}

__device__ __forceinline__ bf16x8 cvt8(float4 a, float4 b) {
    bf16x8 v;
    v[0] = f2bf(a.x); v[1] = f2bf(a.y); v[2] = f2bf(a.z); v[3] = f2bf(a.w);
    v[4] = f2bf(b.x); v[5] = f2bf(b.y); v[6] = f2bf(b.z); v[7] = f2bf(b.w);
    return v;
}

__global__ __launch_bounds__(1024, 4)
void gram_kernel(const float* __restrict__ X, float* __restrict__ out) {
    // block decode: p = 4*g + s.  s=0 -> tile(0,0) chunk g (KC=1024)
    //                             s=1 -> tile(1,1) chunk g (KC=1024)
    //                             s=2,3 -> tile(0,1) chunk 2g+(s-2) (KC=512)
    const int p = blockIdx.x;
    const int g = p >> 2;
    const int s = p & 3;
    const bool diag = (s < 2);
    const int kbase = g * 1024 + (diag ? 0 : (s - 2) * 512);
    const int ITERS = diag ? 32 : 16;
    const int rbaseA = diag ? s * BM : 0;     // A-panel global row base
    // off-diag B panel rows = 256..511

    __shared__ short As[2][PANEL];            // double-buffered
    __shared__ short Bs[2][PANEL];            // unused content on diag blocks

    const int t    = threadIdx.x;
    const int wave = t >> 6;
    const int lane = t & 63;
    const int wm   = wave & 3;                // 4x4 wave grid, 64x64 out each
    const int wn   = wave >> 2;

    // --- staging mapping (block-uniform) ---
    // diag: 1 panel, 4 thr/row, 8 fp32 each.  off: 2 panels, 2 thr/row, 16 fp32.
    const float* ps;                          // global src for this thread
    int wofs;                                 // LDS dst offset within a buffer
    bool wB = false;                          // off-diag: writes B panel?
    if (diag) {
        const int r  = t >> 2;
        const int ko = (t & 3) * 8;
        ps   = X + (size_t)(rbaseA + r) * HW + kbase + ko;
        wofs = r * LDSS + ko;
    } else {
        wB = (t >= 512);
        const int r  = (t & 511) >> 1;
        const int ko = (t & 1) * 16;
        ps   = X + (size_t)((wB ? 256 : 0) + r) * HW + kbase + ko;
        wofs = r * LDSS + ko;
    }

    // --- fragment read offsets (m = lane&15, k-group = lane>>4) ---
    const int fm = lane & 15;
    const int kg = lane >> 4;
    int a_off[4], b_off[4];
#pragma unroll
    for (int i = 0; i < 4; ++i) {
        a_off[i] = (wm * 64 + i * 16 + fm) * LDSS + kg * 8;
        b_off[i] = (wn * 64 + i * 16 + fm) * LDSS + kg * 8;
    }

    f32x4 acc[4][4];
#pragma unroll
    for (int i = 0; i < 4; ++i)
#pragma unroll
        for (int j = 0; j < 4; ++j)
            acc[i][j] = (f32x4){0.f, 0.f, 0.f, 0.f};

    // --- depth-2 prefetch register sets ---
    float4 P[2][4];
#pragma unroll
    for (int q = 0; q < 2; ++q) {             // iters 0 and 1
        const float* sp = ps + q * BK;
        P[q][0] = *(const float4*)(sp + 0);
        P[q][1] = *(const float4*)(sp + 4);
        if (!diag) {
            P[q][2] = *(const float4*)(sp + 8);
            P[q][3] = *(const float4*)(sp + 12);
        }
    }

    // stage iter 0 into buffer 0
    {
        short* w = (wB ? Bs[0] : As[0]) + wofs;
        *(bf16x8*)(w + 0) = cvt8(P[0][0], P[0][1]);
        if (!diag) *(bf16x8*)(w + 8) = cvt8(P[0][2], P[0][3]);
    }
    __syncthreads();

    for (int it = 0; it < ITERS; ++it) {
        const int cur = it & 1;
        const short* Ab = As[cur];
        const short* Bb = diag ? As[cur] : Bs[cur];

        // frag reads from current buffer
        bf16x8 af[4], bfr[4];
#pragma unroll
        for (int i = 0; i < 4; ++i) af[i]  = *(const bf16x8*)(Ab + a_off[i]);
#pragma unroll
        for (int j = 0; j < 4; ++j) bfr[j] = *(const bf16x8*)(Bb + b_off[j]);

        // issue loads for iter it+2 into the just-freed reg set (clamped on
        // the last iters: harmless re-read, data discarded). These stay in
        // flight across the cvt below (vmcnt(N), not 0).
        {
            const int nk = (it + 2 < ITERS) ? (it + 2) : it;   // clamp
            const float* sp = ps + nk * BK;
            P[cur][0] = *(const float4*)(sp + 0);
            P[cur][1] = *(const float4*)(sp + 4);
            if (!diag) {
                P[cur][2] = *(const float4*)(sp + 8);
                P[cur][3] = *(const float4*)(sp + 12);
            }
        }

#pragma unroll
        for (int i = 0; i < 4; ++i)
#pragma unroll
            for (int j = 0; j < 4; ++j)
                acc[i][j] = __builtin_amdgcn_mfma_f32_16x16x32_bf16(
                    af[i], bfr[j], acc[i][j], 0, 0, 0);

        // stage iter it+1 into the other buffer (its regs arrived by now)
        if (it + 1 < ITERS) {
            short* w = (wB ? Bs[1 - cur] : As[1 - cur]) + wofs;
            *(bf16x8*)(w + 0) = cvt8(P[1 - cur][0], P[1 - cur][1]);
            if (!diag) *(bf16x8*)(w + 8) = cvt8(P[1 - cur][2], P[1 - cur][3]);
        }
        __syncthreads();
    }

    // --- epilogue: atomic accumulate partials ---
    // C/D layout (verified m89/m91): col = lane&15, row = (lane>>4)*4 + reg
    const int orow0 = rbaseA + wm * 64 + (lane >> 4) * 4;
    const int ocol0 = (diag ? rbaseA : 256) + wn * 64 + fm;
#pragma unroll
    for (int i = 0; i < 4; ++i)
#pragma unroll
        for (int j = 0; j < 4; ++j)
#pragma unroll
            for (int r = 0; r < 4; ++r) {
                const int row = orow0 + i * 16 + r;
                const int col = ocol0 + j * 16;
                atomicAdd(out + row * CDIM + col, acc[i][j][r]);
                if (!diag)   // mirror into tile (1,0)
                    atomicAdd(out + col * CDIM + row, acc[i][j][r]);
            }
}

extern "C" void kernel_launch(void* const* d_in, const int* in_sizes, int n_in,
                              void* d_out, int out_size, void* d_ws, size_t ws_size,
                              hipStream_t stream) {
    const float* x = (const float*)d_in[0];
    float* out = (float*)d_out;

    // zero the accumulator (harness poisons d_out with 0xAA before every launch)
    hipMemsetAsync(d_out, 0, (size_t)out_size * sizeof(float), stream);

    dim3 grid(256);    // 64 groups x {diag0, diag1, offdiag k-lo, offdiag k-hi}
    dim3 block(1024);
    gram_kernel<<<grid, block, 0, stream>>>(x, out);
}

// Round 5
// 250.255 us; speedup vs baseline: 1.8941x; 1.8941x over previous
//
#include <hip/hip_runtime.h>
#include <hip/hip_bf16.h>
#include <stdint.h>

// Gram matrix: G = X @ X^T, X = [512, 65536] fp32, out = [512, 512] fp32.
// Round 5: three-kernel plan.
//   K1 convert: X fp32 -> bf16 into d_ws (67 MB). Each element converted ONCE.
//   K2 gemm:    m97-verified structure (128x128 tile, 256 thr, width-16
//               global_load_lds into unpadded LDS, 2-barrier K-loop,
//               16 MFMA : 8 ds_read_b128). Symmetric grid: 4 diag tiles x32
//               chunks (KC=2048, launched first for tail balance) + 6 upper
//               tiles x64 chunks (KC=1024) = 512 blocks, all staging 512 KB.
//               Epilogue: row-major coalesced atomics only (8.4M, r3-level).
//   K3 mirror:  copy upper off-diag tiles transposed into lower (1 MB).
// Rationale: r1-r4 show delivered memory throughput for this access pattern
// is ~8 TB/s combined HBM+LLC and scheduling tricks don't move it; the lever
// is LOGICAL bytes: bf16 staging (2x) + symmetry (1.6x): 1.07 GB -> 256 MB.
// r4's scattered mirror atomics (WRITE 451 MB) are replaced by K3.
// Fallback if ws_size < 64 MiB: r1's fused kernel (known-good 135 us).

typedef short bf16x8 __attribute__((ext_vector_type(8)));   // 8 bf16 = 4 VGPRs
typedef float f32x4  __attribute__((ext_vector_type(4)));   // MFMA acc

#define HW    65536
#define CDIM  512

__device__ __forceinline__ short f2bf(float f) {
    __hip_bfloat16 h = __float2bfloat16(f);   // RNE
    short s;
    __builtin_memcpy(&s, &h, sizeof(short));
    return s;
}

__device__ __forceinline__ bf16x8 cvt8(float4 a, float4 b) {
    bf16x8 v;
    v[0] = f2bf(a.x); v[1] = f2bf(a.y); v[2] = f2bf(a.z); v[3] = f2bf(a.w);
    v[4] = f2bf(b.x); v[5] = f2bf(b.y); v[6] = f2bf(b.z); v[7] = f2bf(b.w);
    return v;
}

// async 16B global->LDS copy (DMA; no VGPR round-trip). LDS dest must be
// wave-uniform-base + lane*16 — our staging layout is exactly lane-linear.
typedef const __attribute__((address_space(1))) unsigned int gbl_u32;
typedef __attribute__((address_space(3))) unsigned int lds_u32;
__device__ __forceinline__ void async16(const void* g, void* l) {
    __builtin_amdgcn_global_load_lds((gbl_u32*)g, (lds_u32*)l, 16, 0, 0);
}

// ---------------- K1: fp32 -> bf16 convert ----------------
__global__ __launch_bounds__(256)
void cvt_kernel(const float* __restrict__ X, unsigned short* __restrict__ Xb) {
    const size_t i = ((size_t)blockIdx.x * 256 + threadIdx.x) * 8;
    float4 a = *(const float4*)(X + i);
    float4 b = *(const float4*)(X + i + 4);
    bf16x8 v = cvt8(a, b);
    *(bf16x8*)(Xb + i) = v;
}

// ---------------- K2: symmetric bf16 GEMM ----------------
__global__ __launch_bounds__(256)
void gram_bf16_kernel(const unsigned short* __restrict__ Xb,
                      float* __restrict__ out) {
    // block decode: p<128 -> diag tile d=p>>5, chunk=p&31, KC=2048 (64 iters)
    //               p>=128 -> upper tile o=(p-128)>>6, chunk=(p-128)&63, KC=1024
    const int p = blockIdx.x;
    int ti, tj, kbase, iters;
    if (p < 128) {
        ti = tj = p >> 5;
        kbase = (p & 31) * 2048;
        iters = 64;
    } else {
        const int q = p - 128;
        const int o = q >> 6;
        // upper-triangle off-diag tile pairs
        const int TI[6] = {0, 0, 0, 1, 1, 2};
        const int TJ[6] = {1, 2, 3, 2, 3, 3};
        ti = TI[o]; tj = TJ[o];
        kbase = (q & 63) * 1024;
        iters = 32;
    }
    const bool diag = (ti == tj);

    __shared__ unsigned short As[128 * 32];   // 8 KB, unpadded (lane-linear,
    __shared__ unsigned short Bs[128 * 32];   // required by global_load_lds)

    const int t    = threadIdx.x;
    const int wave = t >> 6;
    const int lane = t & 63;
    const int wm   = wave & 1;                // 2x2 wave grid, 64x64 out each
    const int wn   = wave >> 1;
    const int fm   = lane & 15;
    const int kg   = lane >> 4;

    // staging: thread t covers LDS bytes t*16 (rows 0..63) and t*16+4096
    // (rows 64..127); row = t>>2, col8 = (t&3)*8 bf16.
    const int srow = t >> 2;
    const int scol = (t & 3) * 8;
    const unsigned short* gA = Xb + (size_t)(ti * 128 + srow) * HW + kbase + scol;
    const unsigned short* gB = Xb + (size_t)(tj * 128 + srow) * HW + kbase + scol;
    unsigned short* lA = As + srow * 32 + scol;     // byte ofs = t*16
    unsigned short* lB = Bs + srow * 32 + scol;
    const size_t rstep = (size_t)64 * HW;           // +64 panel rows

    // fragment offsets (A-operand: m = lane&15, k-group = lane>>4, 8 bf16)
    int a_off[4], b_off[4];
#pragma unroll
    for (int i = 0; i < 4; ++i) {
        a_off[i] = (wm * 64 + i * 16 + fm) * 32 + kg * 8;
        b_off[i] = (wn * 64 + i * 16 + fm) * 32 + kg * 8;
    }
    const unsigned short* Bbase = diag ? As : Bs;

    f32x4 acc[4][4];
#pragma unroll
    for (int i = 0; i < 4; ++i)
#pragma unroll
        for (int j = 0; j < 4; ++j)
            acc[i][j] = (f32x4){0.f, 0.f, 0.f, 0.f};

    for (int it = 0; it < iters; ++it) {
        const int ko = it * 32;
        // stage BK=32 slab: 2 issues per panel (rows 0..63, 64..127)
        async16(gA + ko,         lA);
        async16(gA + ko + rstep, lA + 64 * 32);
        if (!diag) {
            async16(gB + ko,         lB);
            async16(gB + ko + rstep, lB + 64 * 32);
        }
        __syncthreads();   // compiler drains vmcnt before s_barrier (m97)

        bf16x8 af[4], bfr[4];
#pragma unroll
        for (int i = 0; i < 4; ++i) af[i]  = *(const bf16x8*)(As + a_off[i]);
#pragma unroll
        for (int j = 0; j < 4; ++j) bfr[j] = *(const bf16x8*)(Bbase + b_off[j]);

#pragma unroll
        for (int i = 0; i < 4; ++i)
#pragma unroll
            for (int j = 0; j < 4; ++j)
                acc[i][j] = __builtin_amdgcn_mfma_f32_16x16x32_bf16(
                    af[i], bfr[j], acc[i][j], 0, 0, 0);

        __syncthreads();   // all waves done reading before next stage
    }

    // epilogue: row-major coalesced atomics (upper/diag tiles only)
    // C/D layout (verified m89/m91): col = lane&15, row = (lane>>4)*4 + reg
    const int orow0 = ti * 128 + wm * 64 + (lane >> 4) * 4;
    const int ocol0 = tj * 128 + wn * 64 + fm;
#pragma unroll
    for (int i = 0; i < 4; ++i)
#pragma unroll
        for (int j = 0; j < 4; ++j)
#pragma unroll
            for (int r = 0; r < 4; ++r)
                atomicAdd(out + (orow0 + i * 16 + r) * CDIM + ocol0 + j * 16,
                          acc[i][j][r]);
}

// ---------------- K3: mirror upper -> lower ----------------
__global__ __launch_bounds__(256)
void mirror_kernel(float* __restrict__ out) {
    const int id = blockIdx.x * 256 + threadIdx.x;   // 0..262143
    const int r = id >> 9;
    const int c = id & 511;
    if ((r >> 7) > (c >> 7))
        out[id] = out[c * CDIM + r];
}

// ---------------- fallback: r1 fused kernel (known-good 135 us) ----------------
#define FKC   2048
#define FBK   32
#define FLDSS 40

__global__ __launch_bounds__(256, 2)
void gram_fallback(const float* __restrict__ X, float* __restrict__ out) {
    const int tile  = blockIdx.x;
    const int ti    = tile >> 2;
    const int tj    = tile & 3;
    const int chunk = blockIdx.y;

    __shared__ short As[128 * FLDSS];
    __shared__ short Bs[128 * FLDSS];

    const int t    = threadIdx.x;
    const int wave = t >> 6;
    const int lane = t & 63;
    const int wm   = wave & 1;
    const int wn   = wave >> 1;

    const int srow  = t >> 1;
    const int shalf = (t & 1) * 16;
    const float* pa = X + (size_t)(ti * 128 + srow) * HW + chunk * FKC + shalf;
    const float* pb = X + (size_t)(tj * 128 + srow) * HW + chunk * FKC + shalf;
    short* wa = As + srow * FLDSS + shalf;
    short* wb = Bs + srow * FLDSS + shalf;

    const int fm = lane & 15;
    const int kg = lane >> 4;
    int a_off[4], b_off[4];
#pragma unroll
    for (int i = 0; i < 4; ++i) {
        a_off[i] = (wm * 64 + i * 16 + fm) * FLDSS + kg * 8;
        b_off[i] = (wn * 64 + i * 16 + fm) * FLDSS + kg * 8;
    }

    f32x4 acc[4][4];
#pragma unroll
    for (int i = 0; i < 4; ++i)
#pragma unroll
        for (int j = 0; j < 4; ++j)
            acc[i][j] = (f32x4){0.f, 0.f, 0.f, 0.f};

    for (int it = 0; it < FKC / FBK; ++it) {
        float4 a0 = *(const float4*)(pa + 0);
        float4 a1 = *(const float4*)(pa + 4);
        float4 a2 = *(const float4*)(pa + 8);
        float4 a3 = *(const float4*)(pa + 12);
        float4 b0 = *(const float4*)(pb + 0);
        float4 b1 = *(const float4*)(pb + 4);
        float4 b2 = *(const float4*)(pb + 8);
        float4 b3 = *(const float4*)(pb + 12);

        bf16x8 va0 = cvt8(a0, a1), va1 = cvt8(a2, a3);
        bf16x8 vb0 = cvt8(b0, b1), vb1 = cvt8(b2, b3);

        __syncthreads();
        *(bf16x8*)(wa + 0) = va0;
        *(bf16x8*)(wa + 8) = va1;
        *(bf16x8*)(wb + 0) = vb0;
        *(bf16x8*)(wb + 8) = vb1;
        __syncthreads();

        bf16x8 af[4], bfr[4];
#pragma unroll
        for (int i = 0; i < 4; ++i) af[i]  = *(const bf16x8*)(As + a_off[i]);
#pragma unroll
        for (int j = 0; j < 4; ++j) bfr[j] = *(const bf16x8*)(Bs + b_off[j]);

#pragma unroll
        for (int i = 0; i < 4; ++i)
#pragma unroll
            for (int j = 0; j < 4; ++j)
                acc[i][j] = __builtin_amdgcn_mfma_f32_16x16x32_bf16(
                    af[i], bfr[j], acc[i][j], 0, 0, 0);

        pa += FBK;
        pb += FBK;
    }

    const int orow0 = ti * 128 + wm * 64 + (lane >> 4) * 4;
    const int ocol0 = tj * 128 + wn * 64 + fm;
#pragma unroll
    for (int i = 0; i < 4; ++i)
#pragma unroll
        for (int j = 0; j < 4; ++j)
#pragma unroll
            for (int r = 0; r < 4; ++r)
                atomicAdd(out + (orow0 + i * 16 + r) * CDIM + ocol0 + j * 16,
                          acc[i][j][r]);
}

extern "C" void kernel_launch(void* const* d_in, const int* in_sizes, int n_in,
                              void* d_out, int out_size, void* d_ws, size_t ws_size,
                              hipStream_t stream) {
    const float* x = (const float*)d_in[0];
    float* out = (float*)d_out;
    const size_t need = (size_t)CDIM * HW * 2;   // 67,108,864 B bf16 copy

    hipMemsetAsync(d_out, 0, (size_t)out_size * sizeof(float), stream);

    if (ws_size >= need) {
        unsigned short* xb = (unsigned short*)d_ws;
        cvt_kernel<<<dim3(16384), dim3(256), 0, stream>>>(x, xb);
        gram_bf16_kernel<<<dim3(512), dim3(256), 0, stream>>>(xb, out);
        mirror_kernel<<<dim3(1024), dim3(256), 0, stream>>>(out);
    } else {
        gram_fallback<<<dim3(16, 32), dim3(256), 0, stream>>>(x, out);
    }
}